// Round 1
// baseline (586.622 us; speedup 1.0000x reference)
//
#include <hip/hip_runtime.h>
#include <math.h>

// Problem constants
#define BB   16
#define CIN  64
#define HH   256
#define WW   256
#define MMOD 16   // modes per dim kept

// d_ws layout (floats):
//   TW2 : [256 w][16 q][2]          = 8192 floats (32 KB)
//   Xg  : [512 mode][64 c][16 b][2] = 1,048,576 floats (4 MB)
//   Yg  : [16 b][64 d][512 mode][2] = 1,048,576 floats (4 MB)

// ---------------------------------------------------------------- twiddles
__global__ __launch_bounds__(256) void k_twiddle(float* __restrict__ TW2) {
    int idx = blockIdx.x * 256 + threadIdx.x;   // 4096 entries
    int w = idx >> 4, q = idx & 15;
    int k = (q * w) & 255;
    float s, c;
    sincospif((float)k * (1.0f / 128.0f), &s, &c);  // sin/cos(2*pi*k/256)
    TW2[2 * idx]     = c;
    TW2[2 * idx + 1] = s;
}

// ------------------------------------------------- forward partial DFT: x -> X
// one block per (b,c) image
__global__ __launch_bounds__(256) void k_fwd(const float* __restrict__ x,
                                             const float* __restrict__ TW2,
                                             float* __restrict__ Xg) {
    __shared__ float  smem[256 * 34];   // x-slab [256][33] then P [256][34]
    __shared__ float2 Ecs[256];         // e^{2*pi*i*k/256}

    const int tid = threadIdx.x;
    const int img = blockIdx.x;         // b*64 + c
    const float* __restrict__ xi = x + (size_t)img * (HH * WW);

    {   // build unit-root table (used in Phase B)
        float s, c;
        sincospif((float)tid * (1.0f / 128.0f), &s, &c);
        Ecs[tid] = make_float2(c, s);
    }

    // ---- Phase A: P[h,q] = sum_w x[h,w] * e^{-2pi i q w/256}, thread h=tid
    float pr[16], pi[16];
#pragma unroll
    for (int q = 0; q < 16; q++) { pr[q] = 0.f; pi[q] = 0.f; }

    for (int w0 = 0; w0 < WW; w0 += 32) {
        __syncthreads();                 // previous slab fully consumed
        // stage 256 rows x 32 cols, coalesced (8 lanes = one 128B row chunk)
#pragma unroll
        for (int j = 0; j < 8; j++) {
            int flat = j * 256 + tid;    // 2048 float4s
            int h = flat >> 3, f4 = flat & 7;
            float4 v = *(const float4*)(xi + (size_t)h * WW + w0 + f4 * 4);
            float* p = &smem[h * 33 + f4 * 4];
            p[0] = v.x; p[1] = v.y; p[2] = v.z; p[3] = v.w;
        }
        __syncthreads();
        const float* __restrict__ twp = TW2 + w0 * 32;   // uniform -> s_load
#pragma unroll 2
        for (int wl = 0; wl < 32; wl++) {
            float xv = smem[tid * 33 + wl];
#pragma unroll
            for (int q = 0; q < 16; q++) {
                float cc = twp[wl * 32 + 2 * q];
                float ss = twp[wl * 32 + 2 * q + 1];
                pr[q] = fmaf(xv,  cc, pr[q]);
                pi[q] = fmaf(xv, -ss, pi[q]);
            }
        }
    }

    // ---- dump P to LDS (padded: row stride 34 floats = 17 complex)
    __syncthreads();
#pragma unroll
    for (int q = 0; q < 16; q++) {
        smem[tid * 34 + 2 * q]     = pr[q];
        smem[tid * 34 + 2 * q + 1] = pi[q];
    }
    __syncthreads();

    // ---- Phase B: X[t,q] = (1/256) sum_h P[h,q] e^{-2pi i t h/256}
    // thread = (tp, q); handles t = tp (top) and t = 240+tp (bottom rows)
    {
        const int q  = tid & 15;
        const int tp = tid >> 4;
        const int t0 = tp;
        const int t1 = 240 + tp;
        float x0r = 0.f, x0i = 0.f, x1r = 0.f, x1i = 0.f;
        for (int h = 0; h < 256; h++) {
            float prv = smem[h * 34 + 2 * q];
            float piv = smem[h * 34 + 2 * q + 1];
            float2 e0 = Ecs[(t0 * h) & 255];
            float2 e1 = Ecs[(t1 * h) & 255];
            x0r = fmaf(prv, e0.x, fmaf(piv,  e0.y, x0r));
            x0i = fmaf(piv, e0.x, fmaf(prv, -e0.y, x0i));
            x1r = fmaf(prv, e1.x, fmaf(piv,  e1.y, x1r));
            x1i = fmaf(piv, e1.x, fmaf(prv, -e1.y, x1i));
        }
        const float sc = 1.0f / 256.0f;
        const int b = img >> 6, c = img & 63;
        size_t o0 = ((size_t)(tp * 16 + q) * 64 + c) * 16 + b;         // mode tp
        size_t o1 = ((size_t)((16 + tp) * 16 + q) * 64 + c) * 16 + b;  // mode 16+tp
        Xg[2 * o0]     = x0r * sc;
        Xg[2 * o0 + 1] = x0i * sc;
        Xg[2 * o1]     = x1r * sc;
        Xg[2 * o1 + 1] = x1i * sc;
    }
}

// ------------------------------------------------- per-mode channel mix: X -> Y
// one block per mode (tIdx*16+q), Y[b,d] = sum_c X[c,b] * W[d,c]
__global__ __launch_bounds__(256) void k_mix(const float* __restrict__ Xg,
                                             const float* __restrict__ w1,
                                             const float* __restrict__ w2,
                                             float* __restrict__ Yg) {
    __shared__ float Xs[64 * 34];    // [c][b] padded (17 complex stride)
    __shared__ float Ws[64 * 130];   // [d][c] padded (65 complex stride)

    const int tid  = threadIdx.x;
    const int mode = blockIdx.x;
    const int tIdx = mode >> 4, q = mode & 15;
    const float* __restrict__ wsel = (tIdx < 16) ? w1 : w2;
    const int t = (tIdx < 16) ? tIdx : (tIdx - 16);

#pragma unroll
    for (int j = 0; j < 4; j++) {    // X: 1024 complex contiguous
        int i = j * 256 + tid;       // c*16+b
        float2 v = ((const float2*)Xg)[(size_t)mode * 1024 + i];
        int c = i >> 4, b = i & 15;
        Xs[c * 34 + 2 * b] = v.x; Xs[c * 34 + 2 * b + 1] = v.y;
    }
#pragma unroll
    for (int j = 0; j < 16; j++) {   // W: 4096 complex strided gather
        int i = j * 256 + tid;       // d*64+c
        float2 v = ((const float2*)wsel)[((size_t)i * 16 + t) * 16 + q];
        int d = i >> 6, c = i & 63;
        Ws[d * 130 + 2 * c] = v.x; Ws[d * 130 + 2 * c + 1] = v.y;
    }
    __syncthreads();

    const int b = tid & 15, dg = tid >> 4;
    float yr[4] = {0, 0, 0, 0}, yi[4] = {0, 0, 0, 0};
    for (int c = 0; c < 64; c++) {
        float xr = Xs[c * 34 + 2 * b];
        float xi = Xs[c * 34 + 2 * b + 1];
#pragma unroll
        for (int j = 0; j < 4; j++) {
            int d = dg + 16 * j;
            float wr = Ws[d * 130 + 2 * c];
            float wi = Ws[d * 130 + 2 * c + 1];
            yr[j] = fmaf(xr, wr, fmaf(xi, -wi, yr[j]));
            yi[j] = fmaf(xr, wi, fmaf(xi,  wr, yi[j]));
        }
    }
#pragma unroll
    for (int j = 0; j < 4; j++) {
        int d = dg + 16 * j;
        size_t o = ((size_t)(b * 64 + d) * 512 + mode);
        Yg[2 * o] = yr[j]; Yg[2 * o + 1] = yi[j];
    }
}

// ------------------------------------------------- inverse: Y -> out
// one block per (b,d) image
__global__ __launch_bounds__(256) void k_inv(const float* __restrict__ Yg,
                                             const float* __restrict__ TW2,
                                             float* __restrict__ out) {
    __shared__ float2 Ecs[256];
    __shared__ float  stage[256 * 33];

    const int tid = threadIdx.x;
    const int img = blockIdx.x;      // b*64 + d
    {
        float s, c;
        sincospif((float)tid * (1.0f / 128.0f), &s, &c);
        Ecs[tid] = make_float2(c, s);
    }
    const float* __restrict__ Y = Yg + (size_t)img * 1024;  // 512 complex

    // ---- Phase D: g[h,q] = sum_{t in S} Y[t,q] e^{+2pi i t h/256}, thread h=tid
    float gr[16], gi[16];
#pragma unroll
    for (int q = 0; q < 16; q++) { gr[q] = 0.f; gi[q] = 0.f; }
    __syncthreads();   // Ecs ready
    const int h = tid;
    for (int j = 0; j < 32; j++) {
        int t = (j < 16) ? j : (224 + j);      // 240..255 for bottom block
        float2 e = Ecs[(t * h) & 255];
#pragma unroll
        for (int q = 0; q < 16; q++) {
            float yr = Y[j * 32 + 2 * q];      // uniform -> s_load
            float yv = Y[j * 32 + 2 * q + 1];
            gr[q] = fmaf(yr, e.x, fmaf(yv, -e.y, gr[q]));
            gi[q] = fmaf(yv, e.x, fmaf(yr,  e.y, gi[q]));
        }
    }

    // ---- Phase E: out[h,w] = (1/256)*(gr0 + 2*sum_q (gr*c - gi*s))
    const size_t obase = (size_t)img * (HH * WW);
    for (int w0 = 0; w0 < WW; w0 += 32) {
        const float* __restrict__ twp = TW2 + w0 * 32;   // uniform -> s_load
#pragma unroll 2
        for (int wl = 0; wl < 32; wl++) {
            float acc = 0.5f * gr[0];
#pragma unroll
            for (int q = 1; q < 16; q++) {
                float cc = twp[wl * 32 + 2 * q];
                float ss = twp[wl * 32 + 2 * q + 1];
                acc = fmaf(gr[q], cc, fmaf(gi[q], -ss, acc));
            }
            stage[h * 33 + wl] = acc * (2.0f / 256.0f);
        }
        __syncthreads();
#pragma unroll
        for (int j = 0; j < 8; j++) {
            int flat = j * 256 + tid;    // 2048 float4s
            int hh = flat >> 3, f4 = flat & 7;
            const float* p = &stage[hh * 33 + f4 * 4];
            float4 v; v.x = p[0]; v.y = p[1]; v.z = p[2]; v.w = p[3];
            *(float4*)(out + obase + (size_t)hh * WW + w0 + f4 * 4) = v;
        }
        __syncthreads();
    }
}

extern "C" void kernel_launch(void* const* d_in, const int* in_sizes, int n_in,
                              void* d_out, int out_size, void* d_ws, size_t ws_size,
                              hipStream_t stream) {
    const float* x  = (const float*)d_in[0];
    const float* w1 = (const float*)d_in[1];
    const float* w2 = (const float*)d_in[2];
    float* outp = (float*)d_out;

    float* TW2 = (float*)d_ws;           // 8192 floats
    float* Xg  = TW2 + 8192;             // 1,048,576 floats
    float* Yg  = Xg + 1048576;           // 1,048,576 floats

    k_twiddle<<<16,   256, 0, stream>>>(TW2);
    k_fwd    <<<BB * CIN, 256, 0, stream>>>(x, TW2, Xg);
    k_mix    <<<512,  256, 0, stream>>>(Xg, w1, w2, Yg);
    k_inv    <<<BB * CIN, 256, 0, stream>>>(Yg, TW2, outp);
}